// Round 1
// baseline (1096.782 us; speedup 1.0000x reference)
//
#include <hip/hip_runtime.h>
#include <stdint.h>

#define BM 128
#define BN 128
#define BKK 32

typedef __attribute__((ext_vector_type(8))) short bf16x8;
typedef __attribute__((ext_vector_type(8))) unsigned short u16x8;
typedef __attribute__((ext_vector_type(4))) float f32x4;
typedef __attribute__((ext_vector_type(4))) int i32x4;

static constexpr int MDIM = 8192;   // B*S
static constexpr int KDIM = 4096;   // I
static constexpr int NDIM = 11008;  // O

// fp32 -> bf16 round-to-nearest-even
static __device__ __forceinline__ unsigned short f2bf(float f) {
  unsigned int u = __builtin_bit_cast(unsigned int, f);
  return (unsigned short)((u + 0x7FFFu + ((u >> 16) & 1u)) >> 16);
}

// fp4 e2m1 code (4 bits: s e1 e0 m) -> fp32. LUT {0,.5,1,1.5,2,3,4,6} w/ sign.
static __device__ __forceinline__ float fp4_val(unsigned int c) {
  unsigned int m = c & 1u, e = (c >> 1) & 3u, s = (c >> 3) & 1u;
  unsigned int bits = e ? (((126u + e) << 23) | (m << 22)) : (m ? 0x3F000000u : 0u);
  bits |= s << 31;
  return __builtin_bit_cast(float, bits);
}

__global__ __launch_bounds__(256) void convert_a_kernel(
    const float4* __restrict__ in, u16x8* __restrict__ out, int n8) {
  int i = blockIdx.x * 256 + threadIdx.x;
  if (i >= n8) return;
  float4 v0 = in[2 * (size_t)i];
  float4 v1 = in[2 * (size_t)i + 1];
  u16x8 r;
  r[0] = f2bf(v0.x); r[1] = f2bf(v0.y); r[2] = f2bf(v0.z); r[3] = f2bf(v0.w);
  r[4] = f2bf(v1.x); r[5] = f2bf(v1.y); r[6] = f2bf(v1.z); r[7] = f2bf(v1.w);
  out[i] = r;
}

// One thread per 32-element scale block: 16 packed int32 -> 32 bf16 values.
__global__ __launch_bounds__(256) void dequant_w_kernel(
    const int* __restrict__ pw, const int* __restrict__ sc,
    unsigned short* __restrict__ wout) {
  int tid = blockIdx.x * 256 + threadIdx.x;
  int o = tid >> 7;          // KDIM/32 = 128 blocks per output row
  int b = tid & 127;
  if (o >= NDIM) return;
  const i32x4* src = (const i32x4*)(pw + (size_t)o * (KDIM / 2) + b * 16);
  unsigned int e = (unsigned int)sc[(size_t)o * (KDIM / 32) + b];
  float scale = __builtin_bit_cast(float, e << 23);  // exp2(e - 127), e in [118,132)
  unsigned short* dst = wout + (size_t)o * KDIM + b * 32;
#pragma unroll
  for (int v = 0; v < 4; ++v) {
    i32x4 w4 = src[v];
    u16x8 r;
#pragma unroll
    for (int j = 0; j < 4; ++j) {
      unsigned int w = (unsigned int)w4[j];
      r[2 * j]     = f2bf(fp4_val(w & 0xFu) * scale);         // even element: low nibble
      r[2 * j + 1] = f2bf(fp4_val((w >> 4) & 0xFu) * scale);  // odd element: high nibble
    }
    *(u16x8*)(dst + 8 * v) = r;
  }
}

#define GLDS16(gp, lp)                                                              \
  __builtin_amdgcn_global_load_lds((const __attribute__((address_space(1))) void*)(gp), \
                                   (__attribute__((address_space(3))) void*)(lp), 16, 0, 0)

// C[M][N] = A[M][K] * W[N][K]^T + bias.  128x128 tile, BK=32, 4 waves (2x2 of 64x64),
// 16x16x32 bf16 MFMA, 4x4 fragments per wave, global_load_lds width-16 staging.
__global__ __launch_bounds__(256) void gemm_bt_kernel(
    const unsigned short* __restrict__ A,   // [MDIM][KDIM] bf16
    const unsigned short* __restrict__ Bw,  // [NDIM][KDIM] bf16
    const float* __restrict__ bias,
    float* __restrict__ C) {
  __shared__ __align__(16) unsigned short As[BM * BKK];
  __shared__ __align__(16) unsigned short Bs[BN * BKK];

  const int t = threadIdx.x;
  const int lane = t & 63;
  const int wave = t >> 6;
  const int wr = wave >> 1, wc = wave & 1;
  const int m0 = blockIdx.y * BM;
  const int n0 = blockIdx.x * BN;

  // staging: linear element idx = t*8 (+2048 for 2nd half); row = idx/32, col = idx%32
  const int r0 = t >> 2;
  const int c8 = (t & 3) * 8;
  const unsigned short* ga = A + (size_t)(m0 + r0) * KDIM + c8;
  const unsigned short* gb = Bw + (size_t)(n0 + r0) * KDIM + c8;
  unsigned short* la = As + t * 8;
  unsigned short* lb = Bs + t * 8;

  const int fl = lane & 15;   // frag row (A: M-row / B: N-col) and C col
  const int fh = lane >> 4;   // frag k-chunk selector

  f32x4 acc[4][4] = {};

  for (int k0 = 0; k0 < KDIM; k0 += BKK) {
    GLDS16(ga + k0, la);
    GLDS16(ga + k0 + (size_t)64 * KDIM, la + 2048);
    GLDS16(gb + k0, lb);
    GLDS16(gb + k0 + (size_t)64 * KDIM, lb + 2048);
    __syncthreads();  // compiler emits s_waitcnt vmcnt(0) before s_barrier

    bf16x8 af[4], bfr[4];
#pragma unroll
    for (int m = 0; m < 4; ++m)
      af[m] = *(const bf16x8*)(As + (wr * 64 + m * 16 + fl) * BKK + fh * 8);
#pragma unroll
    for (int n = 0; n < 4; ++n)
      bfr[n] = *(const bf16x8*)(Bs + (wc * 64 + n * 16 + fl) * BKK + fh * 8);
#pragma unroll
    for (int m = 0; m < 4; ++m)
#pragma unroll
      for (int n = 0; n < 4; ++n)
        acc[m][n] = __builtin_amdgcn_mfma_f32_16x16x32_bf16(af[m], bfr[n], acc[m][n], 0, 0, 0);
    __syncthreads();
  }

  // epilogue: C/D layout col = lane&15, row = (lane>>4)*4 + reg  [m89-verified]
#pragma unroll
  for (int n = 0; n < 4; ++n) {
    const int gn = n0 + wc * 64 + n * 16 + fl;
    const float bv = bias[gn];
#pragma unroll
    for (int m = 0; m < 4; ++m) {
      const int gm = m0 + wr * 64 + m * 16 + fh * 4;
      float* cp = C + (size_t)gm * NDIM + gn;
#pragma unroll
      for (int r = 0; r < 4; ++r)
        cp[(size_t)r * NDIM] = acc[m][n][r] + bv;
    }
  }
}

extern "C" void kernel_launch(void* const* d_in, const int* in_sizes, int n_in,
                              void* d_out, int out_size, void* d_ws, size_t ws_size,
                              hipStream_t stream) {
  const float* inp  = (const float*)d_in[0];
  const float* bias = (const float*)d_in[1];
  const int* pw     = (const int*)d_in[2];
  const int* sc     = (const int*)d_in[3];
  float* out = (float*)d_out;

  unsigned short* a_bf = (unsigned short*)d_ws;                  // 64 MiB
  unsigned short* w_bf = a_bf + (size_t)MDIM * KDIM;             // 86 MiB
  size_t need = ((size_t)MDIM * KDIM + (size_t)NDIM * KDIM) * sizeof(unsigned short);
  if (ws_size < need) return;  // diagnostic: all-zero output => ws too small

  {
    int n8 = MDIM * KDIM / 8;  // 4,194,304 threads, exact multiple of 256
    convert_a_kernel<<<dim3(n8 / 256), dim3(256), 0, stream>>>(
        (const float4*)inp, (u16x8*)a_bf, n8);
  }
  {
    int nthr = NDIM * (KDIM / 32);  // 1,409,024 threads, exact multiple of 256
    dequant_w_kernel<<<dim3(nthr / 256), dim3(256), 0, stream>>>(pw, sc, w_bf);
  }
  gemm_bt_kernel<<<dim3(NDIM / BN, MDIM / BM), dim3(256), 0, stream>>>(
      a_bf, w_bf, bias, out);
}

// Round 2
// 822.600 us; speedup vs baseline: 1.3333x; 1.3333x over previous
//
#include <hip/hip_runtime.h>
#include <stdint.h>

typedef __attribute__((ext_vector_type(8))) short bf16x8;
typedef __attribute__((ext_vector_type(8))) unsigned short u16x8;
typedef __attribute__((ext_vector_type(4))) float f32x4;
typedef __attribute__((ext_vector_type(4))) int i32x4;

static constexpr int MDIM = 8192;   // B*S
static constexpr int KDIM = 4096;   // I
static constexpr int NDIM = 11008;  // O
static constexpr int BM = 256, BN = 256, BK = 32;
static constexpr int NT = KDIM / BK;  // 128 K-tiles
static constexpr int NBX = NDIM / BN; // 43
static constexpr int NBY = MDIM / BM; // 32

// ---------------- prep kernels (unchanged from round 1, verified) ----------------

static __device__ __forceinline__ unsigned short f2bf(float f) {
  unsigned int u = __builtin_bit_cast(unsigned int, f);
  return (unsigned short)((u + 0x7FFFu + ((u >> 16) & 1u)) >> 16);
}

static __device__ __forceinline__ float fp4_val(unsigned int c) {
  unsigned int m = c & 1u, e = (c >> 1) & 3u, s = (c >> 3) & 1u;
  unsigned int bits = e ? (((126u + e) << 23) | (m << 22)) : (m ? 0x3F000000u : 0u);
  bits |= s << 31;
  return __builtin_bit_cast(float, bits);
}

__global__ __launch_bounds__(256) void convert_a_kernel(
    const float4* __restrict__ in, u16x8* __restrict__ out, int n8) {
  int i = blockIdx.x * 256 + threadIdx.x;
  if (i >= n8) return;
  float4 v0 = in[2 * (size_t)i];
  float4 v1 = in[2 * (size_t)i + 1];
  u16x8 r;
  r[0] = f2bf(v0.x); r[1] = f2bf(v0.y); r[2] = f2bf(v0.z); r[3] = f2bf(v0.w);
  r[4] = f2bf(v1.x); r[5] = f2bf(v1.y); r[6] = f2bf(v1.z); r[7] = f2bf(v1.w);
  out[i] = r;
}

__global__ __launch_bounds__(256) void dequant_w_kernel(
    const int* __restrict__ pw, const int* __restrict__ sc,
    unsigned short* __restrict__ wout) {
  int tid = blockIdx.x * 256 + threadIdx.x;
  int o = tid >> 7;
  int b = tid & 127;
  if (o >= NDIM) return;
  const i32x4* src = (const i32x4*)(pw + (size_t)o * (KDIM / 2) + b * 16);
  unsigned int e = (unsigned int)sc[(size_t)o * (KDIM / 32) + b];
  float scale = __builtin_bit_cast(float, e << 23);
  unsigned short* dst = wout + (size_t)o * KDIM + b * 32;
#pragma unroll
  for (int v = 0; v < 4; ++v) {
    i32x4 w4 = src[v];
    u16x8 r;
#pragma unroll
    for (int j = 0; j < 4; ++j) {
      unsigned int w = (unsigned int)w4[j];
      r[2 * j]     = f2bf(fp4_val(w & 0xFu) * scale);
      r[2 * j + 1] = f2bf(fp4_val((w >> 4) & 0xFu) * scale);
    }
    *(u16x8*)(dst + 8 * v) = r;
  }
}

// ---------------- GEMM: 256x256 tile, BK=32, 3-slot LDS ring, 2-tiles-ahead ----------------

#define GLDS16(gp, lp)                                                                  \
  __builtin_amdgcn_global_load_lds((const __attribute__((address_space(1))) void*)(gp), \
                                   (__attribute__((address_space(3))) void*)(lp), 16, 0, 0)

// One K-tile: counted vmcnt + single raw barrier, stage kt+2, 2x16 MFMA clusters.
template <int CS, int NS, bool STAGE, bool LAST>
__device__ __forceinline__ void k_iter(
    unsigned char* lds, int p0, int p1,
    const unsigned short*& gA0, const unsigned short*& gA1,
    const unsigned short*& gB0, const unsigned short*& gB1,
    int baseA, int baseB, f32x4 (&acc)[8][4]) {
  if (LAST) asm volatile("s_waitcnt vmcnt(0)" ::: "memory");
  else      asm volatile("s_waitcnt vmcnt(4)" ::: "memory");
  __builtin_amdgcn_s_barrier();
  asm volatile("" ::: "memory");
  if (STAGE) {
    GLDS16(gA0, lds + NS * 32768 + p0);
    GLDS16(gA1, lds + NS * 32768 + p1);
    GLDS16(gB0, lds + NS * 32768 + 16384 + p0);
    GLDS16(gB1, lds + NS * 32768 + 16384 + p1);
    gA0 += BK; gA1 += BK; gB0 += BK; gB1 += BK;
  }
  const unsigned char* sa = lds + CS * 32768;
  const unsigned char* sb = sa + 16384;
  bf16x8 a[4], b[4];
#pragma unroll
  for (int m = 0; m < 4; ++m) a[m] = *(const bf16x8*)(sa + baseA + m * 1024);
#pragma unroll
  for (int n = 0; n < 4; ++n) b[n] = *(const bf16x8*)(sb + baseB + n * 1024);
  __builtin_amdgcn_s_setprio(1);
#pragma unroll
  for (int m = 0; m < 4; ++m)
#pragma unroll
    for (int n = 0; n < 4; ++n)
      acc[m][n] = __builtin_amdgcn_mfma_f32_16x16x32_bf16(a[m], b[n], acc[m][n], 0, 0, 0);
  __builtin_amdgcn_s_setprio(0);
  bf16x8 a2[4];
#pragma unroll
  for (int m = 0; m < 4; ++m) a2[m] = *(const bf16x8*)(sa + baseA + (4 + m) * 1024);
  __builtin_amdgcn_s_setprio(1);
#pragma unroll
  for (int m = 0; m < 4; ++m)
#pragma unroll
    for (int n = 0; n < 4; ++n)
      acc[4 + m][n] = __builtin_amdgcn_mfma_f32_16x16x32_bf16(a2[m], b[n], acc[4 + m][n], 0, 0, 0);
  __builtin_amdgcn_s_setprio(0);
}

__global__ __launch_bounds__(512, 2) void gemm_mx_kernel(
    const unsigned short* __restrict__ A,   // [MDIM][KDIM] bf16
    const unsigned short* __restrict__ Bw,  // [NDIM][KDIM] bf16
    const float* __restrict__ bias,
    float* __restrict__ C) {
  __shared__ __align__(16) unsigned char lds[3 * 32768];  // 96 KiB: 3 x (A16K + B16K)

  const int t = threadIdx.x;
  const int lane = t & 63;
  const int wave = t >> 6;
  const int wr = wave >> 2;   // 0..1  (M)
  const int wc = wave & 3;    // 0..3  (N)

  // bijective XCD swizzle (grid 1376 % 8 == 0)
  const int bid = blockIdx.x;
  const int swb = (bid & 7) * ((NBX * NBY) / 8) + (bid >> 3);
  const int by = swb / NBX;
  const int bx = swb - by * NBX;
  const int m0 = by * BM, n0 = bx * BN;

  const int fl = lane & 15;
  const int fh = lane >> 4;
  // T2 swizzle folded to per-lane constant: byte = row*64 + (fh*16 ^ ((row>>1)&3)<<4);
  // (row>>1)&3 == (fl>>1)&3 since wr*128, m*16, wc*64, n*16 are all == 0 mod (4<<1)
  const int kof = (fh ^ ((fl >> 1) & 3)) * 16;
  const int baseA = (wr * 128 + fl) * 64 + kof;
  const int baseB = (wc * 64 + fl) * 64 + kof;

  // staging: LDS stays linear; pre-swizzle the GLOBAL source (inverse = same XOR)
  const int p0 = t * 16, p1 = t * 16 + 8192;
  const int rA0 = p0 >> 6, rA1 = p1 >> 6;
  const int kb0 = ((((p0 >> 4) & 3) ^ ((p0 >> 7) & 3)) << 4);
  const int kb1 = ((((p1 >> 4) & 3) ^ ((p1 >> 7) & 3)) << 4);
  const unsigned short* gA0 = A + (size_t)(m0 + rA0) * KDIM + (kb0 >> 1);
  const unsigned short* gA1 = A + (size_t)(m0 + rA1) * KDIM + (kb1 >> 1);
  const unsigned short* gB0 = Bw + (size_t)(n0 + rA0) * KDIM + (kb0 >> 1);
  const unsigned short* gB1 = Bw + (size_t)(n0 + rA1) * KDIM + (kb1 >> 1);

  f32x4 acc[8][4] = {};

  // prologue: stage kt=0 -> slot0, kt=1 -> slot1 (8 loads in flight)
  GLDS16(gA0, lds + p0);
  GLDS16(gA1, lds + p1);
  GLDS16(gB0, lds + 16384 + p0);
  GLDS16(gB1, lds + 16384 + p1);
  gA0 += BK; gA1 += BK; gB0 += BK; gB1 += BK;
  GLDS16(gA0, lds + 32768 + p0);
  GLDS16(gA1, lds + 32768 + p1);
  GLDS16(gB0, lds + 32768 + 16384 + p0);
  GLDS16(gB1, lds + 32768 + 16384 + p1);
  gA0 += BK; gA1 += BK; gB0 += BK; gB1 += BK;

  // main: kt = 0..125, slots cycle (0,1,2); stage kt+2 into (kt+2)%3
  for (int it = 0; it < 42; ++it) {
    k_iter<0, 2, true, false>(lds, p0, p1, gA0, gA1, gB0, gB1, baseA, baseB, acc);
    k_iter<1, 0, true, false>(lds, p0, p1, gA0, gA1, gB0, gB1, baseA, baseB, acc);
    k_iter<2, 1, true, false>(lds, p0, p1, gA0, gA1, gB0, gB1, baseA, baseB, acc);
  }
  // tail: kt=126 (slot0, no stage, counted), kt=127 (slot1, final drain)
  k_iter<0, 2, false, false>(lds, p0, p1, gA0, gA1, gB0, gB1, baseA, baseB, acc);
  k_iter<1, 0, false, true>(lds, p0, p1, gA0, gA1, gB0, gB1, baseA, baseB, acc);

  // epilogue: C/D layout col=lane&15, row=(lane>>4)*4+reg  [verified round 1]
#pragma unroll
  for (int n = 0; n < 4; ++n) {
    const int gn = n0 + wc * 64 + n * 16 + fl;
    const float bv = bias[gn];
#pragma unroll
    for (int m = 0; m < 8; ++m) {
      const int gm = m0 + wr * 128 + m * 16 + fh * 4;
      float* cp = C + (size_t)gm * NDIM + gn;
#pragma unroll
      for (int r = 0; r < 4; ++r)
        cp[(size_t)r * NDIM] = acc[m][n][r] + bv;
    }
  }
}

extern "C" void kernel_launch(void* const* d_in, const int* in_sizes, int n_in,
                              void* d_out, int out_size, void* d_ws, size_t ws_size,
                              hipStream_t stream) {
  const float* inp  = (const float*)d_in[0];
  const float* bias = (const float*)d_in[1];
  const int* pw     = (const int*)d_in[2];
  const int* sc     = (const int*)d_in[3];
  float* out = (float*)d_out;

  unsigned short* a_bf = (unsigned short*)d_ws;
  unsigned short* w_bf = a_bf + (size_t)MDIM * KDIM;
  size_t need = ((size_t)MDIM * KDIM + (size_t)NDIM * KDIM) * sizeof(unsigned short);
  if (ws_size < need) return;

  {
    int n8 = MDIM * KDIM / 8;
    convert_a_kernel<<<dim3(n8 / 256), dim3(256), 0, stream>>>(
        (const float4*)inp, (u16x8*)a_bf, n8);
  }
  {
    int nthr = NDIM * (KDIM / 32);
    dequant_w_kernel<<<dim3(nthr / 256), dim3(256), 0, stream>>>(pw, sc, w_bf);
  }
  gemm_mx_kernel<<<dim3(NBX * NBY), dim3(512), 0, stream>>>(a_bf, w_bf, bias, out);
}